// Round 2
// baseline (30726.736 us; speedup 1.0000x reference)
//
#include <hip/hip_runtime.h>
#include <stdint.h>

#define TT 2048
#define BB 32
#define II 512
#define HH 512
#define BHE (BB * HH)   // 16384 elements per [B,H] slab
#define NWG 64          // workgroups per layer
#define NT 512          // threads per workgroup (8 waves)
#define RING 16         // y0 history ring slots

typedef unsigned short u16;
typedef unsigned int u32;
typedef __attribute__((ext_vector_type(8))) short bf16x8;
typedef __attribute__((ext_vector_type(4))) float f32x4;

__device__ __forceinline__ u16 f2bf(float f) {
  u32 u = __float_as_uint(f);
  return (u16)((u + 0x7fffu + ((u >> 16) & 1u)) >> 16);  // RNE
}
__device__ __forceinline__ float bf2f(u16 h) { return __uint_as_float(((u32)h) << 16); }
__device__ __forceinline__ float sigm(float x) { return 1.f / (1.f + __expf(-x)); }
__device__ __forceinline__ float tanh_(float x) {
  float xc = fminf(fmaxf(x, -15.f), 15.f);
  float e = __expf(-2.f * xc);
  return (1.f - e) / (1.f + e);
}

// ---- prep: x fp32 -> 2-limb bf16 ----
__global__ void k_cvt_x(const float* __restrict__ x, u16* __restrict__ xh, u16* __restrict__ xl) {
  const long n = (long)TT * BB * II;
  long i = ((long)blockIdx.x * 256 + threadIdx.x) * 4;
  const long stride = (long)gridDim.x * 256 * 4;
  for (; i < n; i += stride) {
    float4 v = *(const float4*)(x + i);
    ushort4 h, l;
    h.x = f2bf(v.x); l.x = f2bf(v.x - bf2f(h.x));
    h.y = f2bf(v.y); l.y = f2bf(v.y - bf2f(h.y));
    h.z = f2bf(v.z); l.z = f2bf(v.z - bf2f(h.z));
    h.w = f2bf(v.w); l.w = f2bf(v.w - bf2f(h.w));
    *(ushort4*)(xh + i) = h;
    *(ushort4*)(xl + i) = l;
  }
}

// ---- prep: build gate-permuted, 2-limb weight rows. rr = hidx*4+q, srow = q*512+hidx ----
__global__ void k_build_w(const float* __restrict__ Wih0, const float* __restrict__ Whh0,
                          const float* __restrict__ bih0, const float* __restrict__ bhh0,
                          const float* __restrict__ Wih1, const float* __restrict__ Whh1,
                          const float* __restrict__ bih1, const float* __restrict__ bhh1,
                          u16* __restrict__ WH0, u16* __restrict__ WL0,
                          u16* __restrict__ WH1, u16* __restrict__ WL1,
                          float* __restrict__ bsum0, float* __restrict__ bsum1) {
  const int rr = blockIdx.x & 2047;
  const int layer = blockIdx.x >> 11;
  const float* Wih = layer ? Wih1 : Wih0;
  const float* Whh = layer ? Whh1 : Whh0;
  u16* WH = (layer ? WH1 : WH0) + ((size_t)rr << 10);
  u16* WL = (layer ? WL1 : WL0) + ((size_t)rr << 10);
  const int hidx = rr >> 2, q = rr & 3;
  const int srow = q * HH + hidx;
  const float* si = Wih + (size_t)srow * II;
  const float* sh = Whh + (size_t)srow * HH;
  for (int k = threadIdx.x; k < 512; k += 256) {
    float wi = si[k]; u16 a = f2bf(wi); WH[k] = a;       WL[k] = f2bf(wi - bf2f(a));
    float wh = sh[k]; u16 b = f2bf(wh); WH[512 + k] = b; WL[512 + k] = f2bf(wh - bf2f(b));
  }
  if (threadIdx.x == 0) {
    (layer ? bsum1 : bsum0)[rr] = (layer ? bih1 : bih0)[srow] + (layer ? bhh1 : bhh0)[srow];
  }
}

// ---- prep: h0 -> 2-limb state, reset flag slots (re-runs every call; graph-replay safe) ----
__global__ void k_init(const float* __restrict__ h0,
                       u16* __restrict__ y0h, u16* __restrict__ y0l,
                       u16* __restrict__ h1h, u16* __restrict__ h1l,
                       u32* __restrict__ slots) {
  int i = blockIdx.x * 256 + threadIdx.x;
  if (i < BHE) {
    float v = h0[i]; u16 h = f2bf(v);
    y0h[i] = h; y0l[i] = f2bf(v - bf2f(h));
  } else if (i < 2 * BHE) {
    int j = i - BHE; float v = h0[i]; u16 h = f2bf(v);
    h1h[j] = h; h1l[j] = f2bf(v - bf2f(h));
  }
  if (i < 128) slots[i] = 0;
}

#define MFMA_TO(J, A, B) do { int _j = (J); \
  if (_j == 0)      a0 = __builtin_amdgcn_mfma_f32_16x16x32_bf16((A), (B), a0, 0, 0, 0); \
  else if (_j == 1) a1 = __builtin_amdgcn_mfma_f32_16x16x32_bf16((A), (B), a1, 0, 0, 0); \
  else if (_j == 2) a2 = __builtin_amdgcn_mfma_f32_16x16x32_bf16((A), (B), a2, 0, 0, 0); \
  else              a3 = __builtin_amdgcn_mfma_f32_16x16x32_bf16((A), (B), a3, 0, 0, 0); } while (0)

// ---- persistent scan: blocks 0..63 = layer0, 64..127 = layer1 (pipelined) ----
// WG: 8 waves = (rowblk rb, colblk cb, K-half kh). 16x16 tile per (rb,cb), K=512 per kh.
// Weights (2-limb) live in 128 VGPRs of A-fragments per wave for the whole scan.
__global__ __launch_bounds__(NT, 2) void k_scan(
    const u16* __restrict__ WH0, const u16* __restrict__ WL0,
    const u16* __restrict__ WH1, const u16* __restrict__ WL1,
    const float* __restrict__ bsum0, const float* __restrict__ bsum1,
    const u16* __restrict__ xh, const u16* __restrict__ xl,
    u16* __restrict__ y0h, u16* __restrict__ y0l,
    u16* __restrict__ h1h, u16* __restrict__ h1l,
    const float* __restrict__ c0, float* __restrict__ out,
    u32* __restrict__ slots) {
  __shared__ f32x4 red[4][64];

  const int wgid = blockIdx.x;
  const int layer = wgid >> 6;
  const int wg = wgid & 63;
  const int tid = threadIdx.x;
  const int ln = tid & 63;
  const int wv = tid >> 6;
  const int rb = (wv >> 2) & 1, pg = wv >> 1, kh = wv & 1;
  const int cb = (wv >> 1) & 1;
  const int l15 = ln & 15, l16 = ln >> 4;
  const int k_lane = l16 * 8;
  const int bcol = cb * 16 + l15;                 // D col = lane&15  (batch)
  const int rr = wg * 32 + rb * 16 + l15;         // A row = lane&15  (gate row, permuted)
  const int hidx = wg * 8 + rb * 4 + l16;         // owner lane's h index

  const u16* WH = layer ? WH1 : WH0;
  const u16* WL = layer ? WL1 : WL0;

  // stage this wave's A-fragments (hi+lo limbs) into registers, once
  bf16x8 wah[16], wal[16];
  {
    const u16* ph = WH + ((size_t)rr << 10) + kh * 512 + k_lane;
    const u16* pl = WL + ((size_t)rr << 10) + kh * 512 + k_lane;
#pragma unroll
    for (int kk = 0; kk < 16; ++kk) {
      wah[kk] = *(const bf16x8*)(ph + kk * 32);
      wal[kk] = *(const bf16x8*)(pl + kk * 32);
    }
  }
  const float* bsum = layer ? bsum1 : bsum0;
  f32x4 bias = *(const f32x4*)(bsum + hidx * 4);   // gates i,f,g,o for this lane's h
  float c = c0[layer * BHE + bcol * HH + hidx];

  u32* slotL0 = slots;
  u32* slotL1 = slots + 64;
  float* hnp = out + (size_t)TT * BHE + (size_t)layer * BHE;
  float* cnp = out + (size_t)TT * BHE + 2 * BHE + (size_t)layer * BHE;

  for (int t = 0; t < TT; ++t) {
    // ---- acquire: wave 0 polls per-WG progress slots (lane ln checks WG ln) ----
    if (wv == 0) {
      int needA, needB; u32 tgtA = 0, tgtB = 0;
      if (layer == 0) { needA = (t > 0); tgtA = (u32)t;       needB = (t >= RING); tgtB = (u32)(t - RING + 1); }
      else            { needA = 1;       tgtA = (u32)(t + 1); needB = (t > 0);     tgtB = (u32)t; }
      for (;;) {
        int ok = 1;
        if (needA) ok &= (__hip_atomic_load(&slotL0[ln], __ATOMIC_RELAXED, __HIP_MEMORY_SCOPE_AGENT) >= tgtA);
        if (needB) ok &= (__hip_atomic_load(&slotL1[ln], __ATOMIC_RELAXED, __HIP_MEMORY_SCOPE_AGENT) >= tgtB);
        if (__all(ok)) break;
        __builtin_amdgcn_s_sleep(1);
      }
      __builtin_amdgcn_fence(__ATOMIC_ACQUIRE, "agent");
    }
    __syncthreads();

    // ---- B operand bases: kh=0 reads the "x" half of K, kh=1 the "h" half ----
    const u16 *bh_p, *bl_p;
    if (layer == 0) {
      if (kh == 0) {
        bh_p = xh + (size_t)t * BHE + bcol * II + k_lane;
        bl_p = xl + (size_t)t * BHE + bcol * II + k_lane;
      } else {
        int sl = t & (RING - 1);
        bh_p = y0h + (size_t)sl * BHE + bcol * HH + k_lane;
        bl_p = y0l + (size_t)sl * BHE + bcol * HH + k_lane;
      }
    } else {
      if (kh == 0) {
        int sl = (t + 1) & (RING - 1);
        bh_p = y0h + (size_t)sl * BHE + bcol * HH + k_lane;
        bl_p = y0l + (size_t)sl * BHE + bcol * HH + k_lane;
      } else {
        int sl = t & 1;
        bh_p = h1h + (size_t)sl * BHE + bcol * HH + k_lane;
        bl_p = h1l + (size_t)sl * BHE + bcol * HH + k_lane;
      }
    }

    // ---- gates += Wh*Bh + Wh*Bl + Wl*Bh over this wave's K=512 slice ----
    f32x4 a0 = {0.f, 0.f, 0.f, 0.f}, a1 = a0, a2 = a0, a3 = a0;
#pragma unroll
    for (int kk = 0; kk < 16; ++kk) {
      bf16x8 bh = *(const bf16x8*)(bh_p + kk * 32);
      bf16x8 bl = *(const bf16x8*)(bl_p + kk * 32);
      MFMA_TO((3 * kk + 0) & 3, wah[kk], bh);
      MFMA_TO((3 * kk + 1) & 3, wah[kk], bl);
      MFMA_TO((3 * kk + 2) & 3, wal[kk], bh);
    }
    f32x4 s = a0 + a1; s = s + a2; s = s + a3;

    // ---- cross-wave K-reduction (kh pairs) via LDS ----
    if (kh == 1) red[pg][ln] = s;
    __syncthreads();
    if (kh == 0) {
      s += red[pg][ln];
      float gi = s[0] + bias[0], gf = s[1] + bias[1];
      float gg = s[2] + bias[2], go = s[3] + bias[3];
      float iv = sigm(gi), fv = sigm(gf), gv = tanh_(gg), ov = sigm(go);
      c = fv * c + iv * gv;
      float h = ov * tanh_(c);
      u16 hh_ = f2bf(h);
      float res = h - bf2f(hh_);
      u16 hl_ = f2bf(res);
      if (layer == 0) {
        int sl = (t + 1) & (RING - 1);
        y0h[(size_t)sl * BHE + bcol * HH + hidx] = hh_;
        y0l[(size_t)sl * BHE + bcol * HH + hidx] = hl_;
      } else {
        int sl = (t + 1) & 1;
        h1h[(size_t)sl * BHE + bcol * HH + hidx] = hh_;
        h1l[(size_t)sl * BHE + bcol * HH + hidx] = hl_;
        out[(size_t)t * BHE + (size_t)bcol * HH + hidx] = h;   // y1 fp32
      }
      if (t == TT - 1) { hnp[bcol * HH + hidx] = h; cnp[bcol * HH + hidx] = c; }
    }
    __syncthreads();   // all stores drained (vmcnt(0) before s_barrier) before release

    // ---- release: flush L2 to MALL, publish own progress slot ----
    if (tid == 0) {
      __builtin_amdgcn_fence(__ATOMIC_RELEASE, "agent");
      __hip_atomic_store(&(layer ? slotL1 : slotL0)[wg], (u32)(t + 1),
                         __ATOMIC_RELAXED, __HIP_MEMORY_SCOPE_AGENT);
    }
  }
}

extern "C" void kernel_launch(void* const* d_in, const int* in_sizes, int n_in,
                              void* d_out, int out_size, void* d_ws, size_t ws_size,
                              hipStream_t stream) {
  (void)in_sizes; (void)n_in; (void)out_size; (void)ws_size;
  const float* x    = (const float*)d_in[0];
  const float* h0   = (const float*)d_in[1];
  const float* c0   = (const float*)d_in[2];
  const float* Wih0 = (const float*)d_in[3];
  const float* Whh0 = (const float*)d_in[4];
  const float* bih0 = (const float*)d_in[5];
  const float* bhh0 = (const float*)d_in[6];
  const float* Wih1 = (const float*)d_in[7];
  const float* Whh1 = (const float*)d_in[8];
  const float* bih1 = (const float*)d_in[9];
  const float* bhh1 = (const float*)d_in[10];
  float* out = (float*)d_out;

  char* w = (char*)d_ws;
  size_t off = 0;
  auto alloc = [&](size_t bytes) { void* p = w + off; off += (bytes + 255) & ~(size_t)255; return p; };
  u16* xh    = (u16*)alloc((size_t)TT * BB * II * 2);   // 64 MiB
  u16* xl    = (u16*)alloc((size_t)TT * BB * II * 2);   // 64 MiB
  u16* WH0   = (u16*)alloc((size_t)2048 * 1024 * 2);    // 4 MiB
  u16* WL0   = (u16*)alloc((size_t)2048 * 1024 * 2);
  u16* WH1   = (u16*)alloc((size_t)2048 * 1024 * 2);
  u16* WL1   = (u16*)alloc((size_t)2048 * 1024 * 2);
  float* bsum0 = (float*)alloc(2048 * 4);
  float* bsum1 = (float*)alloc(2048 * 4);
  u16* y0h   = (u16*)alloc((size_t)RING * BHE * 2);     // 512 KiB
  u16* y0l   = (u16*)alloc((size_t)RING * BHE * 2);
  u16* h1h   = (u16*)alloc((size_t)2 * BHE * 2);
  u16* h1l   = (u16*)alloc((size_t)2 * BHE * 2);
  u32* slots = (u32*)alloc(512);
  // total ~145 MiB of ws

  k_cvt_x<<<dim3(2048), dim3(256), 0, stream>>>(x, xh, xl);
  k_build_w<<<dim3(4096), dim3(256), 0, stream>>>(Wih0, Whh0, bih0, bhh0,
                                                  Wih1, Whh1, bih1, bhh1,
                                                  WH0, WL0, WH1, WL1, bsum0, bsum1);
  k_init<<<dim3(128), dim3(256), 0, stream>>>(h0, y0h, y0l, h1h, h1l, slots);
  k_scan<<<dim3(2 * NWG), dim3(NT), 0, stream>>>(WH0, WL0, WH1, WL1, bsum0, bsum1,
                                                 xh, xl, y0h, y0l, h1h, h1l,
                                                 c0, out, slots);
}

// Round 3
// 14333.093 us; speedup vs baseline: 2.1438x; 2.1438x over previous
//
#include <hip/hip_runtime.h>
#include <stdint.h>

#define TT 2048
#define BB 32
#define II 512
#define HH 512
#define BHE (BB * HH)   // 16384 elements per [B,H] slab
#define NWG 64          // workgroups per layer
#define NT 512          // threads per workgroup (8 waves)
#define RING 16         // y0 history ring slots

typedef unsigned short u16;
typedef unsigned int u32;
typedef __attribute__((ext_vector_type(8))) short bf16x8;
typedef __attribute__((ext_vector_type(4))) float f32x4;

__device__ __forceinline__ u16 f2bf(float f) {
  u32 u = __float_as_uint(f);
  return (u16)((u + 0x7fffu + ((u >> 16) & 1u)) >> 16);  // RNE
}
__device__ __forceinline__ float bf2f(u16 h) { return __uint_as_float(((u32)h) << 16); }
__device__ __forceinline__ float sigm(float x) { return 1.f / (1.f + __expf(-x)); }
__device__ __forceinline__ float tanh_(float x) {
  float xc = fminf(fmaxf(x, -15.f), 15.f);
  float e = __expf(-2.f * xc);
  return (1.f - e) / (1.f + e);
}

// L1/L2-bypassing comm accesses (coherence point = MALL; no fences needed)
__device__ __forceinline__ bf16x8 ld_bypass(const u16* p) {
  bf16x8 r;
  asm volatile("global_load_dwordx4 %0, %1, off sc0 sc1" : "=v"(r) : "v"(p) : "memory");
  return r;
}
__device__ __forceinline__ void st_bypass(u16* p, u16 v) {
  u32 vv = v;
  asm volatile("global_store_short %0, %1, off sc0 sc1" :: "v"(p), "v"(vv) : "memory");
}

// ---- prep: x fp32 -> 2-limb bf16 ----
__global__ void k_cvt_x(const float* __restrict__ x, u16* __restrict__ xh, u16* __restrict__ xl) {
  const long n = (long)TT * BB * II;
  long i = ((long)blockIdx.x * 256 + threadIdx.x) * 4;
  const long stride = (long)gridDim.x * 256 * 4;
  for (; i < n; i += stride) {
    float4 v = *(const float4*)(x + i);
    ushort4 h, l;
    h.x = f2bf(v.x); l.x = f2bf(v.x - bf2f(h.x));
    h.y = f2bf(v.y); l.y = f2bf(v.y - bf2f(h.y));
    h.z = f2bf(v.z); l.z = f2bf(v.z - bf2f(h.z));
    h.w = f2bf(v.w); l.w = f2bf(v.w - bf2f(h.w));
    *(ushort4*)(xh + i) = h;
    *(ushort4*)(xl + i) = l;
  }
}

// ---- prep: build gate-permuted, 2-limb weight rows. rr = hidx*4+q, srow = q*512+hidx ----
__global__ void k_build_w(const float* __restrict__ Wih0, const float* __restrict__ Whh0,
                          const float* __restrict__ bih0, const float* __restrict__ bhh0,
                          const float* __restrict__ Wih1, const float* __restrict__ Whh1,
                          const float* __restrict__ bih1, const float* __restrict__ bhh1,
                          u16* __restrict__ WH0, u16* __restrict__ WL0,
                          u16* __restrict__ WH1, u16* __restrict__ WL1,
                          float* __restrict__ bsum0, float* __restrict__ bsum1) {
  const int rr = blockIdx.x & 2047;
  const int layer = blockIdx.x >> 11;
  const float* Wih = layer ? Wih1 : Wih0;
  const float* Whh = layer ? Whh1 : Whh0;
  u16* WH = (layer ? WH1 : WH0) + ((size_t)rr << 10);
  u16* WL = (layer ? WL1 : WL0) + ((size_t)rr << 10);
  const int hidx = rr >> 2, q = rr & 3;
  const int srow = q * HH + hidx;
  const float* si = Wih + (size_t)srow * II;
  const float* sh = Whh + (size_t)srow * HH;
  for (int k = threadIdx.x; k < 512; k += 256) {
    float wi = si[k]; u16 a = f2bf(wi); WH[k] = a;       WL[k] = f2bf(wi - bf2f(a));
    float wh = sh[k]; u16 b = f2bf(wh); WH[512 + k] = b; WL[512 + k] = f2bf(wh - bf2f(b));
  }
  if (threadIdx.x == 0) {
    (layer ? bsum1 : bsum0)[rr] = (layer ? bih1 : bih0)[srow] + (layer ? bhh1 : bhh0)[srow];
  }
}

// ---- prep: h0 -> 2-limb state, reset flag slots (re-runs every call; graph-replay safe) ----
__global__ void k_init(const float* __restrict__ h0,
                       u16* __restrict__ y0h, u16* __restrict__ y0l,
                       u16* __restrict__ h1h, u16* __restrict__ h1l,
                       u32* __restrict__ slots) {
  int i = blockIdx.x * 256 + threadIdx.x;
  if (i < BHE) {
    float v = h0[i]; u16 h = f2bf(v);
    y0h[i] = h; y0l[i] = f2bf(v - bf2f(h));
  } else if (i < 2 * BHE) {
    int j = i - BHE; float v = h0[i]; u16 h = f2bf(v);
    h1h[j] = h; h1l[j] = f2bf(v - bf2f(h));
  }
  if (i < 128) slots[i] = 0;
}

// ---- persistent scan: blocks 0..63 = layer0, 64..127 = layer1 (pipelined) ----
// WG: 8 waves = (colblk cb x K-quarter kq). Each wave computes BOTH 16x16 row tiles
// (gate rows wg*32+[0,16) and +[16,32)) over its K=256 slice -> no duplicate B reads.
// Weights (2-limb) pinned in 128 VGPRs of A-fragments per wave for the whole scan.
__global__ __launch_bounds__(NT, 2) void k_scan(
    const u16* __restrict__ WH0, const u16* __restrict__ WL0,
    const u16* __restrict__ WH1, const u16* __restrict__ WL1,
    const float* __restrict__ bsum0, const float* __restrict__ bsum1,
    const u16* __restrict__ xh, const u16* __restrict__ xl,
    u16* __restrict__ y0h, u16* __restrict__ y0l,
    u16* __restrict__ h1h, u16* __restrict__ h1l,
    const float* __restrict__ c0, float* __restrict__ out,
    u32* __restrict__ slots) {
  __shared__ f32x4 red[8][2][64];   // 16 KiB: per-wave partial sums, 2 row tiles

  const int wgid = blockIdx.x;
  const int layer = wgid >> 6;
  const int wg = wgid & 63;
  const int tid = threadIdx.x;
  const int ln = tid & 63;
  const int wv = tid >> 6;
  const int cb = wv & 1;          // batch half
  const int kq = wv >> 1;         // K quarter (256 wide)
  const int l15 = ln & 15, l16 = ln >> 4;
  const int koff = l16 * 8;       // lane K offset inside a 32-wide MFMA K window
  const int bcol = cb * 16 + l15; // batch column
  const int rr0 = wg * 32 + l15;  // A row, tile 0
  const int rr1 = rr0 + 16;       // A row, tile 1
  const int hidx0 = wg * 8 + l16; // finalize lanes own these h indices
  const int hidx1 = hidx0 + 4;

  const u16* WH = layer ? WH1 : WH0;
  const u16* WL = layer ? WL1 : WL0;

  // ---- stage this wave's A-fragments (hi+lo limbs, both tiles) into registers, once ----
  bf16x8 ah0[8], al0[8], ah1[8], al1[8];
#pragma unroll
  for (int kk = 0; kk < 8; ++kk) {
    const size_t kpos = (size_t)kq * 256 + kk * 32 + koff;
    ah0[kk] = *(const bf16x8*)(WH + (((size_t)rr0) << 10) + kpos);
    al0[kk] = *(const bf16x8*)(WL + (((size_t)rr0) << 10) + kpos);
    ah1[kk] = *(const bf16x8*)(WH + (((size_t)rr1) << 10) + kpos);
    al1[kk] = *(const bf16x8*)(WL + (((size_t)rr1) << 10) + kpos);
  }
#pragma unroll
  for (int kk = 0; kk < 8; ++kk) {   // pin: make values opaque so they stay in VGPRs
    asm volatile("" : "+v"(ah0[kk]), "+v"(al0[kk]), "+v"(ah1[kk]), "+v"(al1[kk]));
  }

  const float* bsum = layer ? bsum1 : bsum0;
  f32x4 bias0 = *(const f32x4*)(bsum + hidx0 * 4);
  f32x4 bias1 = *(const f32x4*)(bsum + hidx1 * 4);
  float c0r = c0[layer * BHE + bcol * HH + hidx0];
  float c1r = c0[layer * BHE + bcol * HH + hidx1];

  u32* slotL0 = slots;
  u32* slotL1 = slots + 64;
  float* hnp = out + (size_t)TT * BHE + (size_t)layer * BHE;
  float* cnp = out + (size_t)TT * BHE + 2 * BHE + (size_t)layer * BHE;

  const bool xpath = (layer == 0) && (kq < 2);   // B comes from cached x, flag-independent

  for (int t = 0; t < TT; ++t) {
    bf16x8 pbh[8], pbl[8];
    if (xpath) {   // prefetch x before the poll (cached, no coherence concern)
      const u16* pxh = xh + (size_t)t * BHE + bcol * II + kq * 256 + koff;
      const u16* pxl = xl + (size_t)t * BHE + bcol * II + kq * 256 + koff;
#pragma unroll
      for (int kk = 0; kk < 8; ++kk) {
        pbh[kk] = *(const bf16x8*)(pxh + kk * 32);
        pbl[kk] = *(const bf16x8*)(pxl + kk * 32);
      }
    }

    // ---- acquire: wave 0 polls per-WG progress slots (lane ln watches WG ln) ----
    if (wv == 0) {
      int needA, needB; u32 tgtA = 0, tgtB = 0;
      if (layer == 0) { needA = (t > 0); tgtA = (u32)t;       needB = (t >= RING); tgtB = (u32)(t - RING + 1); }
      else            { needA = 1;       tgtA = (u32)(t + 1); needB = (t > 0);     tgtB = (u32)t; }
      for (;;) {
        int ok = 1;
        if (needA) ok &= (__hip_atomic_load(&slotL0[ln], __ATOMIC_RELAXED, __HIP_MEMORY_SCOPE_AGENT) >= tgtA);
        if (needB) ok &= (__hip_atomic_load(&slotL1[ln], __ATOMIC_RELAXED, __HIP_MEMORY_SCOPE_AGENT) >= tgtB);
        if (__all(ok)) break;
        __builtin_amdgcn_s_sleep(1);
      }
    }
    __syncthreads();

    if (!xpath) {   // B is cross-WG state: bypass L1/L2, read from MALL
      const u16 *ph, *pl;
      if (layer == 0) {                 // kq 2,3: h-part of K, ring slot t
        const int sl = t & (RING - 1), kloc = (kq - 2) * 256;
        ph = y0h + (size_t)sl * BHE + bcol * HH + kloc + koff;
        pl = y0l + (size_t)sl * BHE + bcol * HH + kloc + koff;
      } else if (kq < 2) {              // layer1 x-part = y0 ring slot t+1
        const int sl = (t + 1) & (RING - 1), kloc = kq * 256;
        ph = y0h + (size_t)sl * BHE + bcol * HH + kloc + koff;
        pl = y0l + (size_t)sl * BHE + bcol * HH + kloc + koff;
      } else {                          // layer1 h-part = h1 pingpong slot t
        const int sl = t & 1, kloc = (kq - 2) * 256;
        ph = h1h + (size_t)sl * BHE + bcol * HH + kloc + koff;
        pl = h1l + (size_t)sl * BHE + bcol * HH + kloc + koff;
      }
#pragma unroll
      for (int kk = 0; kk < 8; ++kk) {
        pbh[kk] = ld_bypass(ph + kk * 32);
        pbl[kk] = ld_bypass(pl + kk * 32);
      }
      __builtin_amdgcn_sched_barrier(0);
      asm volatile("s_waitcnt vmcnt(0)" ::: "memory");
      __builtin_amdgcn_sched_barrier(0);
    }

    // ---- gates += Wh*Bh + Wh*Bl + Wl*Bh, both row tiles, K=256 slice ----
    f32x4 a0 = {0.f, 0.f, 0.f, 0.f}, a1 = a0, a2 = a0, a3 = a0, a4 = a0, a5 = a0;
#pragma unroll
    for (int kk = 0; kk < 8; ++kk) {
      a0 = __builtin_amdgcn_mfma_f32_16x16x32_bf16(ah0[kk], pbh[kk], a0, 0, 0, 0);
      a3 = __builtin_amdgcn_mfma_f32_16x16x32_bf16(ah1[kk], pbh[kk], a3, 0, 0, 0);
      a1 = __builtin_amdgcn_mfma_f32_16x16x32_bf16(ah0[kk], pbl[kk], a1, 0, 0, 0);
      a4 = __builtin_amdgcn_mfma_f32_16x16x32_bf16(ah1[kk], pbl[kk], a4, 0, 0, 0);
      a2 = __builtin_amdgcn_mfma_f32_16x16x32_bf16(al0[kk], pbh[kk], a2, 0, 0, 0);
      a5 = __builtin_amdgcn_mfma_f32_16x16x32_bf16(al1[kk], pbh[kk], a5, 0, 0, 0);
    }
    f32x4 s0 = a0 + a1; s0 = s0 + a2;
    f32x4 s1 = a3 + a4; s1 = s1 + a5;

    // ---- cross-wave K reduction ----
    if (kq != 0) { red[wv][0][ln] = s0; red[wv][1][ln] = s1; }
    __syncthreads();
    if (kq == 0) {
      s0 = s0 + red[cb + 2][0][ln]; s0 = s0 + red[cb + 4][0][ln]; s0 = s0 + red[cb + 6][0][ln];
      s1 = s1 + red[cb + 2][1][ln]; s1 = s1 + red[cb + 4][1][ln]; s1 = s1 + red[cb + 6][1][ln];

      float h0v, h1v;
      {
        const float gi = s0[0] + bias0[0], gf = s0[1] + bias0[1];
        const float gg = s0[2] + bias0[2], go = s0[3] + bias0[3];
        const float iv = sigm(gi), fv = sigm(gf), gv = tanh_(gg), ov = sigm(go);
        c0r = fv * c0r + iv * gv;
        h0v = ov * tanh_(c0r);
      }
      {
        const float gi = s1[0] + bias1[0], gf = s1[1] + bias1[1];
        const float gg = s1[2] + bias1[2], go = s1[3] + bias1[3];
        const float iv = sigm(gi), fv = sigm(gf), gv = tanh_(gg), ov = sigm(go);
        c1r = fv * c1r + iv * gv;
        h1v = ov * tanh_(c1r);
      }
      const u16 h0h = f2bf(h0v), h0l = f2bf(h0v - bf2f(h0h));
      const u16 h1h_ = f2bf(h1v), h1l_ = f2bf(h1v - bf2f(h1h_));

      if (layer == 0) {
        const size_t base = (size_t)((t + 1) & (RING - 1)) * BHE + bcol * HH;
        st_bypass(y0h + base + hidx0, h0h); st_bypass(y0l + base + hidx0, h0l);
        st_bypass(y0h + base + hidx1, h1h_); st_bypass(y0l + base + hidx1, h1l_);
      } else {
        const size_t base = (size_t)((t + 1) & 1) * BHE + bcol * HH;
        st_bypass(h1h + base + hidx0, h0h); st_bypass(h1l + base + hidx0, h0l);
        st_bypass(h1h + base + hidx1, h1h_); st_bypass(h1l + base + hidx1, h1l_);
        out[(size_t)t * BHE + (size_t)bcol * HH + hidx0] = h0v;   // y1 fp32, cached
        out[(size_t)t * BHE + (size_t)bcol * HH + hidx1] = h1v;
      }
      if (t == TT - 1) {
        hnp[bcol * HH + hidx0] = h0v; hnp[bcol * HH + hidx1] = h1v;
        cnp[bcol * HH + hidx0] = c0r; cnp[bcol * HH + hidx1] = c1r;
      }
      asm volatile("s_waitcnt vmcnt(0)" ::: "memory");   // comm stores at MALL before barrier
    }
    __syncthreads();

    // ---- release: publish own progress slot (stores already drained above) ----
    if (tid == 0) {
      __hip_atomic_store(&(layer ? slotL1 : slotL0)[wg], (u32)(t + 1),
                         __ATOMIC_RELAXED, __HIP_MEMORY_SCOPE_AGENT);
    }
  }
}

extern "C" void kernel_launch(void* const* d_in, const int* in_sizes, int n_in,
                              void* d_out, int out_size, void* d_ws, size_t ws_size,
                              hipStream_t stream) {
  (void)in_sizes; (void)n_in; (void)out_size; (void)ws_size;
  const float* x    = (const float*)d_in[0];
  const float* h0   = (const float*)d_in[1];
  const float* c0   = (const float*)d_in[2];
  const float* Wih0 = (const float*)d_in[3];
  const float* Whh0 = (const float*)d_in[4];
  const float* bih0 = (const float*)d_in[5];
  const float* bhh0 = (const float*)d_in[6];
  const float* Wih1 = (const float*)d_in[7];
  const float* Whh1 = (const float*)d_in[8];
  const float* bih1 = (const float*)d_in[9];
  const float* bhh1 = (const float*)d_in[10];
  float* out = (float*)d_out;

  char* w = (char*)d_ws;
  size_t off = 0;
  auto alloc = [&](size_t bytes) { void* p = w + off; off += (bytes + 255) & ~(size_t)255; return p; };
  u16* xh    = (u16*)alloc((size_t)TT * BB * II * 2);   // 64 MiB
  u16* xl    = (u16*)alloc((size_t)TT * BB * II * 2);   // 64 MiB
  u16* WH0   = (u16*)alloc((size_t)2048 * 1024 * 2);    // 4 MiB
  u16* WL0   = (u16*)alloc((size_t)2048 * 1024 * 2);
  u16* WH1   = (u16*)alloc((size_t)2048 * 1024 * 2);
  u16* WL1   = (u16*)alloc((size_t)2048 * 1024 * 2);
  float* bsum0 = (float*)alloc(2048 * 4);
  float* bsum1 = (float*)alloc(2048 * 4);
  u16* y0h   = (u16*)alloc((size_t)RING * BHE * 2);     // 512 KiB
  u16* y0l   = (u16*)alloc((size_t)RING * BHE * 2);
  u16* h1h   = (u16*)alloc((size_t)2 * BHE * 2);
  u16* h1l   = (u16*)alloc((size_t)2 * BHE * 2);
  u32* slots = (u32*)alloc(512);

  k_cvt_x<<<dim3(2048), dim3(256), 0, stream>>>(x, xh, xl);
  k_build_w<<<dim3(4096), dim3(256), 0, stream>>>(Wih0, Whh0, bih0, bhh0,
                                                  Wih1, Whh1, bih1, bhh1,
                                                  WH0, WL0, WH1, WL1, bsum0, bsum1);
  k_init<<<dim3(128), dim3(256), 0, stream>>>(h0, y0h, y0l, h1h, h1l, slots);
  k_scan<<<dim3(2 * NWG), dim3(NT), 0, stream>>>(WH0, WL0, WH1, WL1, bsum0, bsum1,
                                                 xh, xl, y0h, y0l, h1h, h1l,
                                                 c0, out, slots);
}